// Round 5
// baseline (301.597 us; speedup 1.0000x reference)
//
#include <hip/hip_runtime.h>
#include <hip/hip_bf16.h>
#include <math.h>

#define N_NODES 50000
#define N_EDGES 800000
#define HC 128
#define SLOT 64     // max in-degree slot; deg~Poisson(16), P(deg>64)~1e-13

#define BM 128
#define NBX ((N_NODES + BM - 1) / BM)  // 391 gemm blocks
#define NCHK 64                        // edge chunks
#define EPB (N_EDGES / NCHK)           // 12500 edges per chunk
#define NRNG 4                         // dst ranges
#define RNG_N (N_NODES / NRNG)         // 12500 nodes per range
#define RNG_W (RNG_N / 2)              // 6250 packed u32 words per range
#define NW (N_NODES / 2)               // 25000 packed words total
#define NSCAT (NCHK * NRNG)            // 256 scatter/hist blocks

typedef short bh8 __attribute__((ext_vector_type(8)));  // 8 bf16 (4 VGPRs)
typedef float f4 __attribute__((ext_vector_type(4)));   // MFMA C/D
typedef float f2 __attribute__((ext_vector_type(2)));

__device__ __forceinline__ unsigned int pk2(float a, float b) {
  return (unsigned int)__bfloat16_as_ushort(__float2bfloat16(a)) |
         ((unsigned int)__bfloat16_as_ushort(__float2bfloat16(b)) << 16);
}
__device__ __forceinline__ float blo(unsigned int u) { return __uint_as_float(u << 16); }
__device__ __forceinline__ float bhi(unsigned int u) { return __uint_as_float(u & 0xffff0000u); }
__device__ __forceinline__ f2 vmax2(f2 a, f2 b) {
#if __has_builtin(__builtin_elementwise_max)
  return __builtin_elementwise_max(a, b);
#else
  f2 r; r.x = fmaxf(a.x, b.x); r.y = fmaxf(a.y, b.y); return r;
#endif
}

// ---------- K0: [weight transpose+bf16, stats zero] + [2D dst histogram] ----
__global__ __launch_bounds__(256) void k_histprep(
    const float* __restrict__ Wl1, const float* __restrict__ Wr1,
    const float* __restrict__ Wl2, const float* __restrict__ Wr2,
    unsigned short* __restrict__ WtAll,
    float* __restrict__ chsum, float* __restrict__ chsq,
    const int* __restrict__ ei, unsigned int* __restrict__ counts32) {
  __shared__ unsigned int hist[RNG_W];  // 25 KB
  int tid = threadIdx.x, bid = blockIdx.x;  // 256 blocks
  int gid = bid * 256 + tid;
  {
    int m = gid >> 14;
    int idx = gid & 16383;
    const float* src = (m == 0) ? Wl1 : (m == 1) ? Wr1 : (m == 2) ? Wl2 : Wr2;
    int k = idx >> 7, n = idx & 127;
    WtAll[((size_t)m * HC + n) * HC + k] =
        __bfloat16_as_ushort(__float2bfloat16(src[k * HC + n]));
    if (gid < HC) { chsum[gid] = 0.f; chsq[gid] = 0.f; }
  }
  int c = bid >> 2, r = bid & 3;
  int rb = r * RNG_N;
  for (int w = tid; w < RNG_W; w += 256) hist[w] = 0u;
  __syncthreads();
  const int* dstp = ei + N_EDGES + c * EPB;
  for (int g = tid; g < EPB / 4; g += 256) {  // 3125 int4 groups
    int4 d4 = *(const int4*)(dstp + g * 4);
    int dl;
    dl = d4.x - rb; if ((unsigned)dl < RNG_N) atomicAdd(&hist[dl >> 1], (dl & 1) ? 0x10000u : 1u);
    dl = d4.y - rb; if ((unsigned)dl < RNG_N) atomicAdd(&hist[dl >> 1], (dl & 1) ? 0x10000u : 1u);
    dl = d4.z - rb; if ((unsigned)dl < RNG_N) atomicAdd(&hist[dl >> 1], (dl & 1) ? 0x10000u : 1u);
    dl = d4.w - rb; if ((unsigned)dl < RNG_N) atomicAdd(&hist[dl >> 1], (dl & 1) ? 0x10000u : 1u);
  }
  __syncthreads();
  unsigned int* dst = counts32 + (size_t)c * NW + r * RNG_W;
  for (int w = tid; w < RNG_W; w += 256) dst[w] = hist[w];  // plain coalesced
}

// ---------- K1b: exclusive prefix over chunks per dst; deg -> cursor --------
__global__ __launch_bounds__(256) void k_scan(const unsigned int* __restrict__ counts32,
                                              unsigned int* __restrict__ bases32,
                                              int* __restrict__ cursor) {
  int w = blockIdx.x * 256 + threadIdx.x;
  if (w >= NW) return;
  unsigned int a0 = 0, a1 = 0;
#pragma unroll 4
  for (int b = 0; b < NCHK; ++b) {
    unsigned int v = counts32[(size_t)b * NW + w];
    bases32[(size_t)b * NW + w] = a0 | (a1 << 16);
    a0 += v & 0xffffu;
    a1 += v >> 16;
  }
  cursor[2 * w] = (int)a0;      // exact deg, plain store
  cursor[2 * w + 1] = (int)a1;
}

// ---------- K1c: fused [2D slot scatter via LDS ds_add_rtn] + [layer-1 GEMM] --
__global__ __launch_bounds__(256) void k_scat_g1(
    const int* __restrict__ ei, const float* __restrict__ ew,
    const unsigned int* __restrict__ bases32, unsigned int* __restrict__ slots,
    const float* __restrict__ X, const unsigned short* __restrict__ Wt,
    const float* __restrict__ b0, const float* __restrict__ b1,
    unsigned short* __restrict__ Y0b, float* __restrict__ Y1) {
  __shared__ __align__(16) unsigned int lsbuf[16384];  // 64 KB
  int tid = threadIdx.x, bid = blockIdx.x;
  if (bid < NSCAT) {  // ---- scatter role: chunk c, range r ----
    int c = bid >> 2, r = bid & 3;
    int rb = r * RNG_N;
    const unsigned int* bp = bases32 + (size_t)c * NW + r * RNG_W;
    for (int w = tid; w < RNG_W; w += 256) lsbuf[w] = bp[w];
    __syncthreads();
    const int* sp = ei + c * EPB;
    const int* dp = ei + N_EDGES + c * EPB;
    const float* wp = ew + c * EPB;
    for (int g = tid; g < EPB / 4; g += 256) {
      int4 s4 = *(const int4*)(sp + g * 4);
      int4 d4 = *(const int4*)(dp + g * 4);
      float4 w4 = *(const float4*)(wp + g * 4);
      int ss[4] = {s4.x, s4.y, s4.z, s4.w};
      int dd[4] = {d4.x, d4.y, d4.z, d4.w};
      float ww[4] = {w4.x, w4.y, w4.z, w4.w};
#pragma unroll
      for (int i = 0; i < 4; ++i) {
        int dl = dd[i] - rb;
        if ((unsigned)dl < RNG_N) {
          unsigned int old = atomicAdd(&lsbuf[dl >> 1], (dl & 1) ? 0x10000u : 1u);
          unsigned int pos = (dl & 1) ? (old >> 16) : (old & 0xffffu);
          unsigned int wq = min((unsigned int)(ww[i] * 65536.f + 0.5f), 65535u);
          if (pos < SLOT)  // defensive; statistically never taken
            slots[(size_t)dd[i] * SLOT + pos] = ((unsigned int)ss[i] << 16) | wq;
        }
      }
    }
    return;
  }
  // ---- GEMM role: layer-1, X fp32 -> bf16 swizzled LDS; W via LDS ----
  unsigned short* Xls = (unsigned short*)lsbuf;   // 32 KB
  unsigned short* Wls = Xls + 128 * 128;          // 32 KB
  int row0 = (bid - NSCAT) * BM;
  {
    int r = tid >> 1;
    int ks = (tid & 1) * 64;
    int gr = row0 + r;
    const float* xp = X + (size_t)gr * HC + ks;
    int sw = r & 15;
#pragma unroll
    for (int i = 0; i < 4; ++i) {
      float f[16];
      if (gr < N_NODES) {
        *(float4*)&f[0] = *(const float4*)(xp + i * 16);
        *(float4*)&f[4] = *(const float4*)(xp + i * 16 + 4);
        *(float4*)&f[8] = *(const float4*)(xp + i * 16 + 8);
        *(float4*)&f[12] = *(const float4*)(xp + i * 16 + 12);
      } else {
#pragma unroll
        for (int j = 0; j < 16; ++j) f[j] = 0.f;
      }
      int kg = (ks >> 3) + i * 2;
      *(uint4*)&Xls[r * 128 + ((kg ^ sw) * 8)] =
          make_uint4(pk2(f[0], f[1]), pk2(f[2], f[3]), pk2(f[4], f[5]), pk2(f[6], f[7]));
      *(uint4*)&Xls[r * 128 + (((kg + 1) ^ sw) * 8)] =
          make_uint4(pk2(f[8], f[9]), pk2(f[10], f[11]), pk2(f[12], f[13]), pk2(f[14], f[15]));
    }
  }
  int lane = tid & 63;
  int wv = tid >> 6;
  int lrow = lane & 15;
  int lq = lane >> 4;
  int rbase = wv * 32;
#pragma unroll
  for (int half = 0; half < 2; ++half) {
    if (half) __syncthreads();  // all waves done reading Wls(half0)
    {
      int n = tid >> 1;
      int ks2 = (tid & 1) * 64;
      const unsigned short* wp = Wt + half * (HC * HC) + n * HC + ks2;
      int swn = n & 15;
#pragma unroll
      for (int g = 0; g < 8; ++g) {
        uint4 v = *(const uint4*)(wp + g * 8);
        int kg = (ks2 >> 3) + g;
        *(uint4*)&Wls[n * 128 + ((kg ^ swn) * 8)] = v;
      }
    }
    __syncthreads();  // also covers Xls staging for half 0
    f4 acc[2][8];
#pragma unroll
    for (int mt = 0; mt < 2; ++mt)
#pragma unroll
      for (int nt = 0; nt < 8; ++nt) acc[mt][nt] = (f4){0.f, 0.f, 0.f, 0.f};
#pragma unroll
    for (int kk = 0; kk < 4; ++kk) {
      int kg = kk * 4 + lq;
      bh8 a0 = *(const bh8*)&Xls[(rbase + lrow) * 128 + ((kg ^ lrow) * 8)];
      bh8 a1 = *(const bh8*)&Xls[(rbase + 16 + lrow) * 128 + ((kg ^ lrow) * 8)];
#pragma unroll
      for (int nt = 0; nt < 8; ++nt) {
        bh8 b = *(const bh8*)&Wls[(nt * 16 + lrow) * 128 + ((kg ^ lrow) * 8)];
        acc[0][nt] = __builtin_amdgcn_mfma_f32_16x16x32_bf16(a0, b, acc[0][nt], 0, 0, 0);
        acc[1][nt] = __builtin_amdgcn_mfma_f32_16x16x32_bf16(a1, b, acc[1][nt], 0, 0, 0);
      }
    }
    const float* bb = half ? b1 : b0;
    float bv[8];
#pragma unroll
    for (int nt = 0; nt < 8; ++nt) bv[nt] = bb[nt * 16 + lrow];
#pragma unroll
    for (int mt = 0; mt < 2; ++mt) {
#pragma unroll
      for (int rr = 0; rr < 4; ++rr) {
        int gr = row0 + rbase + mt * 16 + lq * 4 + rr;
        if (gr < N_NODES) {
          if (half == 0) {
#pragma unroll
            for (int nt = 0; nt < 8; ++nt)
              Y0b[(size_t)gr * HC + nt * 16 + lrow] =
                  __bfloat16_as_ushort(__float2bfloat16(acc[mt][nt][rr] + bv[nt]));
          } else {
#pragma unroll
            for (int nt = 0; nt < 8; ++nt)
              Y1[(size_t)gr * HC + nt * 16 + lrow] = acc[mt][nt][rr] + bv[nt];
          }
        }
      }
    }
  }
}

// ---------- K2: layer-2 GEMM — bf16 X in (BN+ELU on staging), LDS-staged W ----
__global__ __launch_bounds__(256) void k_gemm2(
    const unsigned short* __restrict__ Xb, const unsigned short* __restrict__ Wt,
    const float* __restrict__ b0, const float* __restrict__ b1,
    unsigned char* __restrict__ Y0f8, float* __restrict__ Y1,
    const float* __restrict__ chsum, const float* __restrict__ chsq,
    const float* __restrict__ gamma, const float* __restrict__ beta) {
  __shared__ __align__(16) unsigned short Xls[128 * 128];  // 32 KB
  __shared__ __align__(16) unsigned short Wls[128 * 128];  // 32 KB
  __shared__ float ssc[HC], ssh[HC];
  int tid = threadIdx.x;
  if (tid < HC) {
    float mu = chsum[tid] * (1.f / N_NODES);
    float var = chsq[tid] * (1.f / N_NODES) - mu * mu;  // biased, jnp.var
    float sc = gamma[tid] * rsqrtf(var + 1e-5f);
    ssc[tid] = sc;
    ssh[tid] = beta[tid] - mu * sc;
  }
  __syncthreads();
  int row0 = blockIdx.x * BM;
  {  // stage X tile: decode bf16 -> BN+ELU -> bf16, swizzled
    int r = tid >> 1;
    int ks = (tid & 1) * 64;
    int gr = row0 + r;
    const unsigned short* xp = Xb + (size_t)gr * HC + ks;
    int sw = r & 15;
#pragma unroll
    for (int i = 0; i < 4; ++i) {
      float f[16];
      if (gr < N_NODES) {
        uint4 ua = *(const uint4*)(xp + i * 16);
        uint4 ub = *(const uint4*)(xp + i * 16 + 8);
        f[0] = blo(ua.x); f[1] = bhi(ua.x); f[2] = blo(ua.y); f[3] = bhi(ua.y);
        f[4] = blo(ua.z); f[5] = bhi(ua.z); f[6] = blo(ua.w); f[7] = bhi(ua.w);
        f[8] = blo(ub.x); f[9] = bhi(ub.x); f[10] = blo(ub.y); f[11] = bhi(ub.y);
        f[12] = blo(ub.z); f[13] = bhi(ub.z); f[14] = blo(ub.w); f[15] = bhi(ub.w);
      } else {
#pragma unroll
        for (int j = 0; j < 16; ++j) f[j] = 0.f;
      }
#pragma unroll
      for (int j = 0; j < 16; ++j) {
        float y = fmaf(f[j], ssc[ks + i * 16 + j], ssh[ks + i * 16 + j]);
        f[j] = (y > 0.f) ? y : (__expf(y) - 1.f);  // elu
      }
      int kg = (ks >> 3) + i * 2;
      *(uint4*)&Xls[r * 128 + ((kg ^ sw) * 8)] =
          make_uint4(pk2(f[0], f[1]), pk2(f[2], f[3]), pk2(f[4], f[5]), pk2(f[6], f[7]));
      *(uint4*)&Xls[r * 128 + (((kg + 1) ^ sw) * 8)] =
          make_uint4(pk2(f[8], f[9]), pk2(f[10], f[11]), pk2(f[12], f[13]), pk2(f[14], f[15]));
    }
  }
  int lane = tid & 63;
  int wv = tid >> 6;
  int lrow = lane & 15;
  int lq = lane >> 4;
  int rbase = wv * 32;
#pragma unroll
  for (int half = 0; half < 2; ++half) {
    if (half) __syncthreads();  // all waves done reading Wls(half0)
    {
      int n = tid >> 1;
      int ks = (tid & 1) * 64;
      const unsigned short* wp = Wt + half * (HC * HC) + n * HC + ks;
      int swn = n & 15;
#pragma unroll
      for (int g = 0; g < 8; ++g) {
        uint4 v = *(const uint4*)(wp + g * 8);
        int kg = (ks >> 3) + g;
        *(uint4*)&Wls[n * 128 + ((kg ^ swn) * 8)] = v;
      }
    }
    __syncthreads();  // also covers Xls staging for half 0
    f4 acc[2][8];
#pragma unroll
    for (int mt = 0; mt < 2; ++mt)
#pragma unroll
      for (int nt = 0; nt < 8; ++nt) acc[mt][nt] = (f4){0.f, 0.f, 0.f, 0.f};
#pragma unroll
    for (int kk = 0; kk < 4; ++kk) {
      int kg = kk * 4 + lq;
      bh8 a0 = *(const bh8*)&Xls[(rbase + lrow) * 128 + ((kg ^ lrow) * 8)];
      bh8 a1 = *(const bh8*)&Xls[(rbase + 16 + lrow) * 128 + ((kg ^ lrow) * 8)];
#pragma unroll
      for (int nt = 0; nt < 8; ++nt) {
        bh8 b = *(const bh8*)&Wls[(nt * 16 + lrow) * 128 + ((kg ^ lrow) * 8)];
        acc[0][nt] = __builtin_amdgcn_mfma_f32_16x16x32_bf16(a0, b, acc[0][nt], 0, 0, 0);
        acc[1][nt] = __builtin_amdgcn_mfma_f32_16x16x32_bf16(a1, b, acc[1][nt], 0, 0, 0);
      }
    }
    const float* bb = half ? b1 : b0;
    float bv[8];
#pragma unroll
    for (int nt = 0; nt < 8; ++nt) bv[nt] = bb[nt * 16 + lrow];
#pragma unroll
    for (int mt = 0; mt < 2; ++mt) {
#pragma unroll
      for (int rr = 0; rr < 4; ++rr) {
        int gr = row0 + rbase + mt * 16 + lq * 4 + rr;
        if (gr < N_NODES) {
          if (half == 0) {
#pragma unroll
            for (int nt = 0; nt < 8; ++nt) {
              float v = acc[mt][nt][rr] + bv[nt];
              int p = __builtin_amdgcn_cvt_pk_fp8_f32(v, v, 0, false);
              Y0f8[(size_t)gr * HC + nt * 16 + lrow] = (unsigned char)(p & 0xff);
            }
          } else {
#pragma unroll
            for (int nt = 0; nt < 8; ++nt)
              Y1[(size_t)gr * HC + nt * 16 + lrow] = acc[mt][nt][rr] + bv[nt];
          }
        }
      }
    }
  }
}

// ---------- K3: fused attention + aggregation (R16: deep pipeline + fetch diet) --
// R16: (1) two-phase 8-deep move-free prefetch (~1.5 quads latency cover);
// (2) raw-tick edge weights with 1/65536 folded into pre-scaled We (kills a
// v_mul per fetch); (3) shfl clamp dropped (HIP shfl wraps srcLane mod width;
// garbage rows only consumed under valid=false, indices stay inside ws).
template <int FINAL, int F8>
__global__ __launch_bounds__(256) void k_gat(
    const void* __restrict__ xlv, const float* __restrict__ xr,
    const int* __restrict__ cursor, const unsigned int* __restrict__ slots,
    const float* __restrict__ We, const float* __restrict__ att,
    const float* __restrict__ bias, void* __restrict__ out,
    const float* __restrict__ emb, const unsigned short* __restrict__ h1p,
    const float* __restrict__ chsum, const float* __restrict__ chsq,
    const float* __restrict__ gamma, const float* __restrict__ beta) {
  int g = threadIdx.x >> 5;
  int lane = threadIdx.x & 31;
  int n = blockIdx.x * 8 + g;
  int fi = n * 32 + lane;  // float4/uint2 index into [N,128]
  const uint2* xl2 = (const uint2*)xlv;               // bf16 rows
  const unsigned int* xf = (const unsigned int*)xlv;  // fp8 rows
  float4 xr4 = ((const float4*)xr)[fi];
  float4 we4 = ((const float4*)We)[lane];
  float4 at4 = ((const float4*)att)[lane];
  const float LOG2E = 1.4426950408889634f;
  const float WSC = 1.f / 65536.f;  // folded into We: edge weights stay raw ticks
  f2 xr01 = {xr4.x, xr4.y}, xr23 = {xr4.z, xr4.w};
  f2 we01 = {we4.x * WSC, we4.y * WSC}, we23 = {we4.z * WSC, we4.w * WSC};
  f2 at01 = {at4.x * LOG2E, at4.y * LOG2E}, at23 = {at4.z * LOG2E, at4.w * LOG2E};
  int deg = min(cursor[n], SLOT);  // dense cursor
  int base = n * SLOT;
  int deg32 = min(deg, 32);

  unsigned int ev = (lane < deg32) ? slots[base + lane] : 0u;
  float wsum = (float)(ev & 0xffffu);  // raw ticks; lanes >= deg32 contribute 0
#pragma unroll
  for (int m = 16; m >= 1; m >>= 1) wsum += __shfl_xor(wsum, m);

  float l = 0.f;
  f2 o01 = {0.f, 0.f}, o23 = {0.f, 0.f};

  auto decode = [&](uint2 gc, f2& a, f2& b) {
    if (F8) {
      a = __builtin_amdgcn_cvt_pk_f32_fp8((int)gc.x, false);
      b = __builtin_amdgcn_cvt_pk_f32_fp8((int)gc.x, true);
    } else {
      a = (f2){blo(gc.x), bhi(gc.x)};
      b = (f2){blo(gc.y), bhi(gc.y)};
    }
  };
  auto edge_body = [&](float w, uint2 gc, bool valid) {
    f2 a, b;
    decode(gc, a, b);
    f2 m01 = (a + xr01) + w * we01;   // pk_add + pk_fma (we pre-scaled)
    f2 m23 = (b + xr23) + w * we23;
    m01 = vmax2(m01, m01 * 0.2f);     // leaky: pk_mul + pk_max
    m23 = vmax2(m23, m23 * 0.2f);
    f2 dp = m01 * at01 + m23 * at23;  // pk_mul + pk_fma (log2-domain)
    float p = dp.x + dp.y;
    p += __shfl_xor(p, 1);
    p += __shfl_xor(p, 2);
    p += __shfl_xor(p, 4);            // 8-lane head group holds the logit
#if __has_builtin(__builtin_amdgcn_exp2f)
    float e = valid ? __builtin_amdgcn_exp2f(p) : 0.f;
#else
    float e = valid ? __expf(p * 0.6931471805599453f) : 0.f;
#endif
    l += e;
    o01 = o01 + e * a;                // pk_fma
    o23 = o23 + e * b;
  };
  auto fetch = [&](int j, uint2& qq, float& ww) {
    unsigned int evj = __shfl(ev, j, 32);  // srcLane wraps mod 32 (garbage masked)
    ww = (float)(evj & 0xffffu);           // raw ticks
    int s = (int)(evj >> 16);
    if (F8) qq.x = xf[s * 32 + lane];
    else qq = xl2[s * 32 + lane];
  };

  if (deg32 > 0) {
    // two-phase 8-deep pipeline, move-free: process A | refill A | process B | refill B
    uint2 a0, a1, a2, a3, b0, b1, b2, b3;
    float u0, u1, u2, u3, v0, v1, v2, v3;
    fetch(0, a0, u0); fetch(1, a1, u1); fetch(2, a2, u2); fetch(3, a3, u3);
    fetch(4, b0, v0); fetch(5, b1, v1); fetch(6, b2, v2); fetch(7, b3, v3);
    for (int b = 0; b < deg32; b += 8) {
      edge_body(u0, a0, true);
      edge_body(u1, a1, b + 1 < deg32);
      edge_body(u2, a2, b + 2 < deg32);
      edge_body(u3, a3, b + 3 < deg32);
      fetch(b + 8, a0, u0); fetch(b + 9, a1, u1);
      fetch(b + 10, a2, u2); fetch(b + 11, a3, u3);
      edge_body(v0, b0, b + 4 < deg32);
      edge_body(v1, b1, b + 5 < deg32);
      edge_body(v2, b2, b + 6 < deg32);
      edge_body(v3, b3, b + 7 < deg32);
      fetch(b + 12, b0, v0); fetch(b + 13, b1, v1);
      fetch(b + 14, b2, v2); fetch(b + 15, b3, v3);
    }
  }
  if (deg > 32) {  // rare tail (P ~ 1e-4 per node): direct loads
    for (int j = base + 32; j < base + deg; ++j) {
      unsigned int evj = slots[j];
      float w = (float)(evj & 0xffffu);  // raw ticks
      wsum += w;
      int s = (int)(evj >> 16);
      uint2 gc;
      if (F8) gc.x = xf[s * 32 + lane];
      else gc = xl2[s * 32 + lane];
      edge_body(w, gc, true);
    }
  }
  {  // self-loop: attr = mean of incoming edge weights (0 if none); raw-tick mean
    float wself = (deg > 0) ? wsum / (float)deg : 0.f;
    uint2 gs;
    if (F8) gs.x = xf[n * 32 + lane];
    else gs = xl2[n * 32 + lane];
    edge_body(wself, gs, true);
  }

  float inv = 1.f / l;
  float4 o = make_float4(o01.x, o01.y, o23.x, o23.y);
  float4 b4 = ((const float4*)bias)[lane];
  float4 r;
  r.x = fmaf(o.x, inv, b4.x);
  r.y = fmaf(o.y, inv, b4.y);
  r.z = fmaf(o.z, inv, b4.z);
  r.w = fmaf(o.w, inv, b4.w);
  if (FINAL) {
    float4 e4 = ((const float4*)emb)[fi];
    uint2 hh = ((const uint2*)h1p)[fi];
    float4 h4;
    h4.x = blo(hh.x); h4.y = bhi(hh.x); h4.z = blo(hh.y); h4.w = bhi(hh.y);
    float4 cs = ((const float4*)chsum)[lane];
    float4 cq = ((const float4*)chsq)[lane];
    float4 gm = ((const float4*)gamma)[lane];
    float4 bt = ((const float4*)beta)[lane];
    const float invN = 1.f / N_NODES;
    float4 sc4, sh4;
    {
      float mu = cs.x * invN, var = cq.x * invN - mu * mu;
      sc4.x = gm.x * rsqrtf(var + 1e-5f); sh4.x = bt.x - mu * sc4.x;
      mu = cs.y * invN; var = cq.y * invN - mu * mu;
      sc4.y = gm.y * rsqrtf(var + 1e-5f); sh4.y = bt.y - mu * sc4.y;
      mu = cs.z * invN; var = cq.z * invN - mu * mu;
      sc4.z = gm.z * rsqrtf(var + 1e-5f); sh4.z = bt.z - mu * sc4.z;
      mu = cs.w * invN; var = cq.w * invN - mu * mu;
      sc4.w = gm.w * rsqrtf(var + 1e-5f); sh4.w = bt.w - mu * sc4.w;
    }
    float4 h;  // recompute BN+ELU of bf16 h1 (consistent with gemm2's input)
    h.x = fmaf(h4.x, sc4.x, sh4.x);
    h.y = fmaf(h4.y, sc4.y, sh4.y);
    h.z = fmaf(h4.z, sc4.z, sh4.z);
    h.w = fmaf(h4.w, sc4.w, sh4.w);
    h.x = (h.x > 0.f) ? h.x : (__expf(h.x) - 1.f);
    h.y = (h.y > 0.f) ? h.y : (__expf(h.y) - 1.f);
    h.z = (h.z > 0.f) ? h.z : (__expf(h.z) - 1.f);
    h.w = (h.w > 0.f) ? h.w : (__expf(h.w) - 1.f);
    const float k3 = 1.f / 3.f;
    r.x = (e4.x + h.x + r.x) * k3;
    r.y = (e4.y + h.y + r.y) * k3;
    r.z = (e4.z + h.z + r.z) * k3;
    r.w = (e4.w + h.w + r.w) * k3;
    ((float4*)out)[fi] = r;
  } else {
    ((uint2*)out)[fi] = make_uint2(pk2(r.x, r.y), pk2(r.z, r.w));  // h1 bf16
  }
}

// ---------- K4: BN stats over bf16 h1 (uint pair loads + per-channel atomics) --
#define BN_ROWS 200
__global__ __launch_bounds__(256) void k_bnstats(const unsigned short* __restrict__ h1b,
                                                 float* __restrict__ chsum,
                                                 float* __restrict__ chsq) {
  int c2 = threadIdx.x & 63;  // channel pair (2*c2, 2*c2+1)
  int g = threadIdx.x >> 6;   // 0..3
  int r0 = blockIdx.x * BN_ROWS;
  float s0 = 0.f, s1 = 0.f, q0 = 0.f, q1 = 0.f;
  const unsigned int* h32 = (const unsigned int*)h1b;
  for (int r = r0 + g; r < r0 + BN_ROWS; r += 4) {
    unsigned int u = h32[(size_t)r * 64 + c2];
    float a = blo(u), b = bhi(u);
    s0 += a; q0 += a * a;
    s1 += b; q1 += b * b;
  }
  __shared__ float sh[256][4];
  sh[threadIdx.x][0] = s0; sh[threadIdx.x][1] = q0;
  sh[threadIdx.x][2] = s1; sh[threadIdx.x][3] = q1;
  __syncthreads();
  if (g == 0) {
    float ts0 = 0.f, tq0 = 0.f, ts1 = 0.f, tq1 = 0.f;
#pragma unroll
    for (int gg = 0; gg < 4; ++gg) {
      ts0 += sh[gg * 64 + c2][0]; tq0 += sh[gg * 64 + c2][1];
      ts1 += sh[gg * 64 + c2][2]; tq1 += sh[gg * 64 + c2][3];
    }
    atomicAdd(chsum + 2 * c2, ts0);
    atomicAdd(chsq + 2 * c2, tq0);
    atomicAdd(chsum + 2 * c2 + 1, ts1);
    atomicAdd(chsq + 2 * c2 + 1, tq1);
  }
}

extern "C" void kernel_launch(void* const* d_in, const int* in_sizes, int n_in,
                              void* d_out, int out_size, void* d_ws, size_t ws_size,
                              hipStream_t stream) {
  const float* emb = (const float*)d_in[0];
  const int* ei = (const int*)d_in[1];
  const float* ew = (const float*)d_in[2];
  const float* Wl1 = (const float*)d_in[3];
  const float* bl1 = (const float*)d_in[4];
  const float* Wr1 = (const float*)d_in[5];
  const float* br1 = (const float*)d_in[6];
  const float* We1 = (const float*)d_in[7];
  const float* att1 = (const float*)d_in[8];
  const float* bias1 = (const float*)d_in[9];
  const float* gamma1 = (const float*)d_in[10];
  const float* beta1 = (const float*)d_in[11];
  const float* Wl2 = (const float*)d_in[12];
  const float* bl2 = (const float*)d_in[13];
  const float* Wr2 = (const float*)d_in[14];
  const float* br2 = (const float*)d_in[15];
  const float* We2 = (const float*)d_in[16];
  const float* att2 = (const float*)d_in[17];
  const float* bias2 = (const float*)d_in[18];
  float* out = (float*)d_out;

  char* wsb = (char*)d_ws;
  size_t off = 0;
  auto alloc = [&](size_t bytes) -> void* {
    void* p = (void*)(wsb + off);
    off += (bytes + 255) & ~(size_t)255;
    return p;
  };
  int* cursor = (int*)alloc((size_t)N_NODES * 4);                           // 200 KB dense
  float* chsum = (float*)alloc(HC * 4);
  float* chsq = (float*)alloc(HC * 4);
  unsigned short* WtAll = (unsigned short*)alloc((size_t)4 * HC * HC * 2);  // 128 KB
  unsigned int* counts32 = (unsigned int*)alloc((size_t)NCHK * NW * 4);     // 6.4 MB
  unsigned int* bases32 = (unsigned int*)alloc((size_t)NCHK * NW * 4);      // 6.4 MB
  unsigned int* slots = (unsigned int*)alloc((size_t)N_NODES * SLOT * 4);   // 12.8 MB
  unsigned short* xlb = (unsigned short*)alloc((size_t)N_NODES * HC * 2);   // bf16 xl1
  unsigned char* xlf8 = (unsigned char*)alloc((size_t)N_NODES * HC);        // fp8 xl2
  float* xr = (float*)alloc((size_t)N_NODES * HC * 4);
  unsigned short* h1b = (unsigned short*)alloc((size_t)N_NODES * HC * 2);   // bf16 h1

  // wprep + 2D histogram fused (256 blocks)
  k_histprep<<<NSCAT, 256, 0, stream>>>(Wl1, Wr1, Wl2, Wr2, WtAll, chsum, chsq,
                                        ei, counts32);
  k_scan<<<(NW + 255) / 256, 256, 0, stream>>>(counts32, bases32, cursor);
  // 2D slot scatter fused with layer-1 GEMM (64 KB LDS -> 2 blocks/CU)
  k_scat_g1<<<NSCAT + NBX, 256, 0, stream>>>(ei, ew, bases32, slots, emb, WtAll,
                                             bl1, br1, xlb, xr);
  k_gat<0, 0><<<N_NODES / 8, 256, 0, stream>>>(xlb, xr, cursor, slots, We1, att1,
                                               bias1, (void*)h1b, nullptr, nullptr,
                                               nullptr, nullptr, nullptr, nullptr);
  k_bnstats<<<N_NODES / BN_ROWS, 256, 0, stream>>>(h1b, chsum, chsq);
  k_gemm2<<<NBX, 256, 0, stream>>>(h1b, WtAll + 2 * HC * HC, bl2, br2, xlf8, xr,
                                   chsum, chsq, gamma1, beta1);
  k_gat<1, 1><<<N_NODES / 8, 256, 0, stream>>>(xlf8, xr, cursor, slots, We2, att2,
                                               bias2, (void*)out, emb, h1b,
                                               chsum, chsq, gamma1, beta1);
}

// Round 6
// 278.294 us; speedup vs baseline: 1.0837x; 1.0837x over previous
//
#include <hip/hip_runtime.h>
#include <hip/hip_bf16.h>
#include <math.h>

#define N_NODES 50000
#define N_EDGES 800000
#define HC 128
#define SLOT 64     // max in-degree slot; deg~Poisson(16), P(deg>64)~1e-13

#define BM 128
#define NBX ((N_NODES + BM - 1) / BM)  // 391 gemm blocks
#define NCHK 64                        // edge chunks
#define EPB (N_EDGES / NCHK)           // 12500 edges per chunk
#define NRNG 4                         // dst ranges
#define RNG_N (N_NODES / NRNG)         // 12500 nodes per range
#define RNG_W (RNG_N / 2)              // 6250 packed u32 words per range
#define NW (N_NODES / 2)               // 25000 packed words total
#define NSCAT (NCHK * NRNG)            // 256 scatter/hist blocks
#define NB2 ((NW + 255) / 256)         // 98 scan blocks (512 nodes each)

typedef short bh8 __attribute__((ext_vector_type(8)));  // 8 bf16 (4 VGPRs)
typedef float f4 __attribute__((ext_vector_type(4)));   // MFMA C/D
typedef float f2 __attribute__((ext_vector_type(2)));

__device__ __forceinline__ unsigned int pk2(float a, float b) {
  return (unsigned int)__bfloat16_as_ushort(__float2bfloat16(a)) |
         ((unsigned int)__bfloat16_as_ushort(__float2bfloat16(b)) << 16);
}
__device__ __forceinline__ float blo(unsigned int u) { return __uint_as_float(u << 16); }
__device__ __forceinline__ float bhi(unsigned int u) { return __uint_as_float(u & 0xffff0000u); }
__device__ __forceinline__ f2 vmax2(f2 a, f2 b) {
#if __has_builtin(__builtin_elementwise_max)
  return __builtin_elementwise_max(a, b);
#else
  f2 r; r.x = fmaxf(a.x, b.x); r.y = fmaxf(a.y, b.y); return r;
#endif
}

// ---------- K0: [weight transpose+bf16, stats zero] + [2D dst histogram] ----
__global__ __launch_bounds__(256) void k_histprep(
    const float* __restrict__ Wl1, const float* __restrict__ Wr1,
    const float* __restrict__ Wl2, const float* __restrict__ Wr2,
    unsigned short* __restrict__ WtAll,
    float* __restrict__ chsum, float* __restrict__ chsq,
    const int* __restrict__ ei, unsigned int* __restrict__ counts32) {
  __shared__ unsigned int hist[RNG_W];  // 25 KB
  int tid = threadIdx.x, bid = blockIdx.x;  // 256 blocks
  int gid = bid * 256 + tid;
  {
    int m = gid >> 14;
    int idx = gid & 16383;
    const float* src = (m == 0) ? Wl1 : (m == 1) ? Wr1 : (m == 2) ? Wl2 : Wr2;
    int k = idx >> 7, n = idx & 127;
    WtAll[((size_t)m * HC + n) * HC + k] =
        __bfloat16_as_ushort(__float2bfloat16(src[k * HC + n]));
    if (gid < HC) { chsum[gid] = 0.f; chsq[gid] = 0.f; }
  }
  int c = bid >> 2, r = bid & 3;
  int rb = r * RNG_N;
  for (int w = tid; w < RNG_W; w += 256) hist[w] = 0u;
  __syncthreads();
  const int* dstp = ei + N_EDGES + c * EPB;
  for (int g = tid; g < EPB / 4; g += 256) {  // 3125 int4 groups
    int4 d4 = *(const int4*)(dstp + g * 4);
    int dl;
    dl = d4.x - rb; if ((unsigned)dl < RNG_N) atomicAdd(&hist[dl >> 1], (dl & 1) ? 0x10000u : 1u);
    dl = d4.y - rb; if ((unsigned)dl < RNG_N) atomicAdd(&hist[dl >> 1], (dl & 1) ? 0x10000u : 1u);
    dl = d4.z - rb; if ((unsigned)dl < RNG_N) atomicAdd(&hist[dl >> 1], (dl & 1) ? 0x10000u : 1u);
    dl = d4.w - rb; if ((unsigned)dl < RNG_N) atomicAdd(&hist[dl >> 1], (dl & 1) ? 0x10000u : 1u);
  }
  __syncthreads();
  unsigned int* dst = counts32 + (size_t)c * NW + r * RNG_W;
  for (int w = tid; w < RNG_W; w += 256) dst[w] = hist[w];  // plain coalesced
}

// ---------- K1b: prefix over chunks per dst; deg -> cursor; + per-block
// degree histogram (R17: feeds the degree counting-sort, 65 keys) --------
__global__ __launch_bounds__(256) void k_scan(const unsigned int* __restrict__ counts32,
                                              unsigned int* __restrict__ bases32,
                                              int* __restrict__ cursor,
                                              int* __restrict__ counts2) {
  __shared__ int dh[80];
  int tid = threadIdx.x;
  int w = blockIdx.x * 256 + tid;
  if (tid < 80) dh[tid] = 0;
  __syncthreads();
  if (w < NW) {
    unsigned int a0 = 0, a1 = 0;
#pragma unroll 4
    for (int b = 0; b < NCHK; ++b) {
      unsigned int v = counts32[(size_t)b * NW + w];
      bases32[(size_t)b * NW + w] = a0 | (a1 << 16);
      a0 += v & 0xffffu;
      a1 += v >> 16;
    }
    cursor[2 * w] = (int)a0;      // exact deg, plain store
    cursor[2 * w + 1] = (int)a1;
    atomicAdd(&dh[min((int)a0, SLOT)], 1);  // LDS degree histogram
    atomicAdd(&dh[min((int)a1, SLOT)], 1);
  }
  __syncthreads();
  if (tid <= SLOT) counts2[blockIdx.x * 72 + tid] = dh[tid];
}

// ---------- K1b2: tiny global prefix for the degree sort (65 keys x 98 blocks) --
__global__ __launch_bounds__(256) void k_dprefix(const int* __restrict__ counts2,
                                                 int* __restrict__ bases2) {
  __shared__ int colsum[80], cbase[80];
  int d = threadIdx.x;
  if (d <= SLOT) {
    int s = 0;
    for (int b = 0; b < NB2; ++b) s += counts2[b * 72 + d];
    colsum[d] = s;
  }
  __syncthreads();
  if (d == 0) {
    int a = 0;
    for (int i = 0; i <= SLOT; ++i) { cbase[i] = a; a += colsum[i]; }
  }
  __syncthreads();
  if (d <= SLOT) {
    int a = cbase[d];
    for (int b = 0; b < NB2; ++b) { bases2[b * 72 + d] = a; a += counts2[b * 72 + d]; }
  }
}

// ---------- K1c: fused [2D slot scatter] + [layer-1 GEMM] + [degree sort] ----
__global__ __launch_bounds__(256) void k_scat_g1(
    const int* __restrict__ ei, const float* __restrict__ ew,
    const unsigned int* __restrict__ bases32, unsigned int* __restrict__ slots,
    const float* __restrict__ X, const unsigned short* __restrict__ Wt,
    const float* __restrict__ b0, const float* __restrict__ b1,
    unsigned short* __restrict__ Y0b, float* __restrict__ Y1,
    const int* __restrict__ cursor, const int* __restrict__ bases2,
    int* __restrict__ perm) {
  __shared__ __align__(16) unsigned int lsbuf[16384];  // 64 KB
  int tid = threadIdx.x, bid = blockIdx.x;
  if (bid >= NSCAT + NBX) {  // ---- degree-sort scatter role (98 blocks) ----
    int b2 = bid - NSCAT - NBX;
    int* dcur = (int*)lsbuf;
    if (tid <= SLOT) dcur[tid] = bases2[b2 * 72 + tid];
    __syncthreads();
    for (int i = tid; i < 512; i += 256) {
      int nn = b2 * 512 + i;
      if (nn < N_NODES) {
        int d = min(cursor[nn], SLOT);
        int pos = atomicAdd(&dcur[d], 1);  // LDS ds_add_rtn
        perm[pos] = nn;                    // stable counting sort
      }
    }
    return;
  }
  if (bid < NSCAT) {  // ---- edge scatter role: chunk c, range r ----
    int c = bid >> 2, r = bid & 3;
    int rb = r * RNG_N;
    const unsigned int* bp = bases32 + (size_t)c * NW + r * RNG_W;
    for (int w = tid; w < RNG_W; w += 256) lsbuf[w] = bp[w];
    __syncthreads();
    const int* sp = ei + c * EPB;
    const int* dp = ei + N_EDGES + c * EPB;
    const float* wp = ew + c * EPB;
    for (int g = tid; g < EPB / 4; g += 256) {
      int4 s4 = *(const int4*)(sp + g * 4);
      int4 d4 = *(const int4*)(dp + g * 4);
      float4 w4 = *(const float4*)(wp + g * 4);
      int ss[4] = {s4.x, s4.y, s4.z, s4.w};
      int dd[4] = {d4.x, d4.y, d4.z, d4.w};
      float ww[4] = {w4.x, w4.y, w4.z, w4.w};
#pragma unroll
      for (int i = 0; i < 4; ++i) {
        int dl = dd[i] - rb;
        if ((unsigned)dl < RNG_N) {
          unsigned int old = atomicAdd(&lsbuf[dl >> 1], (dl & 1) ? 0x10000u : 1u);
          unsigned int pos = (dl & 1) ? (old >> 16) : (old & 0xffffu);
          unsigned int wq = min((unsigned int)(ww[i] * 65536.f + 0.5f), 65535u);
          if (pos < SLOT)  // defensive; statistically never taken
            slots[(size_t)dd[i] * SLOT + pos] = ((unsigned int)ss[i] << 16) | wq;
        }
      }
    }
    return;
  }
  // ---- GEMM role: layer-1, X fp32 -> bf16 swizzled LDS; W via LDS ----
  unsigned short* Xls = (unsigned short*)lsbuf;   // 32 KB
  unsigned short* Wls = Xls + 128 * 128;          // 32 KB
  int row0 = (bid - NSCAT) * BM;
  {
    int r = tid >> 1;
    int ks = (tid & 1) * 64;
    int gr = row0 + r;
    const float* xp = X + (size_t)gr * HC + ks;
    int sw = r & 15;
#pragma unroll
    for (int i = 0; i < 4; ++i) {
      float f[16];
      if (gr < N_NODES) {
        *(float4*)&f[0] = *(const float4*)(xp + i * 16);
        *(float4*)&f[4] = *(const float4*)(xp + i * 16 + 4);
        *(float4*)&f[8] = *(const float4*)(xp + i * 16 + 8);
        *(float4*)&f[12] = *(const float4*)(xp + i * 16 + 12);
      } else {
#pragma unroll
        for (int j = 0; j < 16; ++j) f[j] = 0.f;
      }
      int kg = (ks >> 3) + i * 2;
      *(uint4*)&Xls[r * 128 + ((kg ^ sw) * 8)] =
          make_uint4(pk2(f[0], f[1]), pk2(f[2], f[3]), pk2(f[4], f[5]), pk2(f[6], f[7]));
      *(uint4*)&Xls[r * 128 + (((kg + 1) ^ sw) * 8)] =
          make_uint4(pk2(f[8], f[9]), pk2(f[10], f[11]), pk2(f[12], f[13]), pk2(f[14], f[15]));
    }
  }
  int lane = tid & 63;
  int wv = tid >> 6;
  int lrow = lane & 15;
  int lq = lane >> 4;
  int rbase = wv * 32;
#pragma unroll
  for (int half = 0; half < 2; ++half) {
    if (half) __syncthreads();  // all waves done reading Wls(half0)
    {
      int n = tid >> 1;
      int ks2 = (tid & 1) * 64;
      const unsigned short* wp = Wt + half * (HC * HC) + n * HC + ks2;
      int swn = n & 15;
#pragma unroll
      for (int g = 0; g < 8; ++g) {
        uint4 v = *(const uint4*)(wp + g * 8);
        int kg = (ks2 >> 3) + g;
        *(uint4*)&Wls[n * 128 + ((kg ^ swn) * 8)] = v;
      }
    }
    __syncthreads();  // also covers Xls staging for half 0
    f4 acc[2][8];
#pragma unroll
    for (int mt = 0; mt < 2; ++mt)
#pragma unroll
      for (int nt = 0; nt < 8; ++nt) acc[mt][nt] = (f4){0.f, 0.f, 0.f, 0.f};
#pragma unroll
    for (int kk = 0; kk < 4; ++kk) {
      int kg = kk * 4 + lq;
      bh8 a0 = *(const bh8*)&Xls[(rbase + lrow) * 128 + ((kg ^ lrow) * 8)];
      bh8 a1 = *(const bh8*)&Xls[(rbase + 16 + lrow) * 128 + ((kg ^ lrow) * 8)];
#pragma unroll
      for (int nt = 0; nt < 8; ++nt) {
        bh8 b = *(const bh8*)&Wls[(nt * 16 + lrow) * 128 + ((kg ^ lrow) * 8)];
        acc[0][nt] = __builtin_amdgcn_mfma_f32_16x16x32_bf16(a0, b, acc[0][nt], 0, 0, 0);
        acc[1][nt] = __builtin_amdgcn_mfma_f32_16x16x32_bf16(a1, b, acc[1][nt], 0, 0, 0);
      }
    }
    const float* bb = half ? b1 : b0;
    float bv[8];
#pragma unroll
    for (int nt = 0; nt < 8; ++nt) bv[nt] = bb[nt * 16 + lrow];
#pragma unroll
    for (int mt = 0; mt < 2; ++mt) {
#pragma unroll
      for (int rr = 0; rr < 4; ++rr) {
        int gr = row0 + rbase + mt * 16 + lq * 4 + rr;
        if (gr < N_NODES) {
          if (half == 0) {
#pragma unroll
            for (int nt = 0; nt < 8; ++nt)
              Y0b[(size_t)gr * HC + nt * 16 + lrow] =
                  __bfloat16_as_ushort(__float2bfloat16(acc[mt][nt][rr] + bv[nt]));
          } else {
#pragma unroll
            for (int nt = 0; nt < 8; ++nt)
              Y1[(size_t)gr * HC + nt * 16 + lrow] = acc[mt][nt][rr] + bv[nt];
          }
        }
      }
    }
  }
}

// ---------- K2: layer-2 GEMM — bf16 X in (BN+ELU on staging), LDS-staged W ----
__global__ __launch_bounds__(256) void k_gemm2(
    const unsigned short* __restrict__ Xb, const unsigned short* __restrict__ Wt,
    const float* __restrict__ b0, const float* __restrict__ b1,
    unsigned char* __restrict__ Y0f8, float* __restrict__ Y1,
    const float* __restrict__ chsum, const float* __restrict__ chsq,
    const float* __restrict__ gamma, const float* __restrict__ beta) {
  __shared__ __align__(16) unsigned short Xls[128 * 128];  // 32 KB
  __shared__ __align__(16) unsigned short Wls[128 * 128];  // 32 KB
  __shared__ float ssc[HC], ssh[HC];
  int tid = threadIdx.x;
  if (tid < HC) {
    float mu = chsum[tid] * (1.f / N_NODES);
    float var = chsq[tid] * (1.f / N_NODES) - mu * mu;  // biased, jnp.var
    float sc = gamma[tid] * rsqrtf(var + 1e-5f);
    ssc[tid] = sc;
    ssh[tid] = beta[tid] - mu * sc;
  }
  __syncthreads();
  int row0 = blockIdx.x * BM;
  {  // stage X tile: decode bf16 -> BN+ELU -> bf16, swizzled
    int r = tid >> 1;
    int ks = (tid & 1) * 64;
    int gr = row0 + r;
    const unsigned short* xp = Xb + (size_t)gr * HC + ks;
    int sw = r & 15;
#pragma unroll
    for (int i = 0; i < 4; ++i) {
      float f[16];
      if (gr < N_NODES) {
        uint4 ua = *(const uint4*)(xp + i * 16);
        uint4 ub = *(const uint4*)(xp + i * 16 + 8);
        f[0] = blo(ua.x); f[1] = bhi(ua.x); f[2] = blo(ua.y); f[3] = bhi(ua.y);
        f[4] = blo(ua.z); f[5] = bhi(ua.z); f[6] = blo(ua.w); f[7] = bhi(ua.w);
        f[8] = blo(ub.x); f[9] = bhi(ub.x); f[10] = blo(ub.y); f[11] = bhi(ub.y);
        f[12] = blo(ub.z); f[13] = bhi(ub.z); f[14] = blo(ub.w); f[15] = bhi(ub.w);
      } else {
#pragma unroll
        for (int j = 0; j < 16; ++j) f[j] = 0.f;
      }
#pragma unroll
      for (int j = 0; j < 16; ++j) {
        float y = fmaf(f[j], ssc[ks + i * 16 + j], ssh[ks + i * 16 + j]);
        f[j] = (y > 0.f) ? y : (__expf(y) - 1.f);  // elu
      }
      int kg = (ks >> 3) + i * 2;
      *(uint4*)&Xls[r * 128 + ((kg ^ sw) * 8)] =
          make_uint4(pk2(f[0], f[1]), pk2(f[2], f[3]), pk2(f[4], f[5]), pk2(f[6], f[7]));
      *(uint4*)&Xls[r * 128 + (((kg + 1) ^ sw) * 8)] =
          make_uint4(pk2(f[8], f[9]), pk2(f[10], f[11]), pk2(f[12], f[13]), pk2(f[14], f[15]));
    }
  }
  int lane = tid & 63;
  int wv = tid >> 6;
  int lrow = lane & 15;
  int lq = lane >> 4;
  int rbase = wv * 32;
#pragma unroll
  for (int half = 0; half < 2; ++half) {
    if (half) __syncthreads();  // all waves done reading Wls(half0)
    {
      int n = tid >> 1;
      int ks = (tid & 1) * 64;
      const unsigned short* wp = Wt + half * (HC * HC) + n * HC + ks;
      int swn = n & 15;
#pragma unroll
      for (int g = 0; g < 8; ++g) {
        uint4 v = *(const uint4*)(wp + g * 8);
        int kg = (ks >> 3) + g;
        *(uint4*)&Wls[n * 128 + ((kg ^ swn) * 8)] = v;
      }
    }
    __syncthreads();  // also covers Xls staging for half 0
    f4 acc[2][8];
#pragma unroll
    for (int mt = 0; mt < 2; ++mt)
#pragma unroll
      for (int nt = 0; nt < 8; ++nt) acc[mt][nt] = (f4){0.f, 0.f, 0.f, 0.f};
#pragma unroll
    for (int kk = 0; kk < 4; ++kk) {
      int kg = kk * 4 + lq;
      bh8 a0 = *(const bh8*)&Xls[(rbase + lrow) * 128 + ((kg ^ lrow) * 8)];
      bh8 a1 = *(const bh8*)&Xls[(rbase + 16 + lrow) * 128 + ((kg ^ lrow) * 8)];
#pragma unroll
      for (int nt = 0; nt < 8; ++nt) {
        bh8 b = *(const bh8*)&Wls[(nt * 16 + lrow) * 128 + ((kg ^ lrow) * 8)];
        acc[0][nt] = __builtin_amdgcn_mfma_f32_16x16x32_bf16(a0, b, acc[0][nt], 0, 0, 0);
        acc[1][nt] = __builtin_amdgcn_mfma_f32_16x16x32_bf16(a1, b, acc[1][nt], 0, 0, 0);
      }
    }
    const float* bb = half ? b1 : b0;
    float bv[8];
#pragma unroll
    for (int nt = 0; nt < 8; ++nt) bv[nt] = bb[nt * 16 + lrow];
#pragma unroll
    for (int mt = 0; mt < 2; ++mt) {
#pragma unroll
      for (int rr = 0; rr < 4; ++rr) {
        int gr = row0 + rbase + mt * 16 + lq * 4 + rr;
        if (gr < N_NODES) {
          if (half == 0) {
#pragma unroll
            for (int nt = 0; nt < 8; ++nt) {
              float v = acc[mt][nt][rr] + bv[nt];
              int p = __builtin_amdgcn_cvt_pk_fp8_f32(v, v, 0, false);
              Y0f8[(size_t)gr * HC + nt * 16 + lrow] = (unsigned char)(p & 0xff);
            }
          } else {
#pragma unroll
            for (int nt = 0; nt < 8; ++nt)
              Y1[(size_t)gr * HC + nt * 16 + lrow] = acc[mt][nt][rr] + bv[nt];
          }
        }
      }
    }
  }
}

// ---------- K3: fused attention + aggregation ----------
// R17: R15 body restored (4-deep clamped prefetch, 40 VGPR — R16's 8-deep
// crossed the 64-VGPR occupancy cliff and unclamped shfl wrap cost +24MB
// FETCH). Kept from R16: raw-tick weights (1/65536 folded into We) and
// log2-domain att. New: nodes processed in degree-sorted order via perm[]
// so the 2 nodes sharing a wave have ~equal degree (kills max(d1,d2) tax).
template <int FINAL, int F8>
__global__ __launch_bounds__(256) void k_gat(
    const void* __restrict__ xlv, const float* __restrict__ xr,
    const int* __restrict__ cursor, const unsigned int* __restrict__ slots,
    const int* __restrict__ perm,
    const float* __restrict__ We, const float* __restrict__ att,
    const float* __restrict__ bias, void* __restrict__ out,
    const float* __restrict__ emb, const unsigned short* __restrict__ h1p,
    const float* __restrict__ chsum, const float* __restrict__ chsq,
    const float* __restrict__ gamma, const float* __restrict__ beta) {
  int g = threadIdx.x >> 5;
  int lane = threadIdx.x & 31;
  int n = perm[blockIdx.x * 8 + g];  // degree-sorted node id
  int fi = n * 32 + lane;  // float4/uint2 index into [N,128]
  const uint2* xl2 = (const uint2*)xlv;               // bf16 rows
  const unsigned int* xf = (const unsigned int*)xlv;  // fp8 rows
  float4 xr4 = ((const float4*)xr)[fi];
  float4 we4 = ((const float4*)We)[lane];
  float4 at4 = ((const float4*)att)[lane];
  const float LOG2E = 1.4426950408889634f;
  const float WSC = 1.f / 65536.f;  // folded into We: edge weights stay raw ticks
  f2 xr01 = {xr4.x, xr4.y}, xr23 = {xr4.z, xr4.w};
  f2 we01 = {we4.x * WSC, we4.y * WSC}, we23 = {we4.z * WSC, we4.w * WSC};
  f2 at01 = {at4.x * LOG2E, at4.y * LOG2E}, at23 = {at4.z * LOG2E, at4.w * LOG2E};
  int deg = min(cursor[n], SLOT);  // dense cursor
  int base = n * SLOT;
  int deg32 = min(deg, 32);

  unsigned int ev = (lane < deg32) ? slots[base + lane] : 0u;
  float wsum = (float)(ev & 0xffffu);  // raw ticks; lanes >= deg32 contribute 0
#pragma unroll
  for (int m = 16; m >= 1; m >>= 1) wsum += __shfl_xor(wsum, m);

  float l = 0.f;
  f2 o01 = {0.f, 0.f}, o23 = {0.f, 0.f};

  auto decode = [&](uint2 gc, f2& a, f2& b) {
    if (F8) {
      a = __builtin_amdgcn_cvt_pk_f32_fp8((int)gc.x, false);
      b = __builtin_amdgcn_cvt_pk_f32_fp8((int)gc.x, true);
    } else {
      a = (f2){blo(gc.x), bhi(gc.x)};
      b = (f2){blo(gc.y), bhi(gc.y)};
    }
  };
  auto edge_body = [&](float w, uint2 gc, bool valid) {
    f2 a, b;
    decode(gc, a, b);
    f2 m01 = (a + xr01) + w * we01;   // pk_add + pk_fma (we pre-scaled)
    f2 m23 = (b + xr23) + w * we23;
    m01 = vmax2(m01, m01 * 0.2f);     // leaky: pk_mul + pk_max
    m23 = vmax2(m23, m23 * 0.2f);
    f2 dp = m01 * at01 + m23 * at23;  // pk_mul + pk_fma (log2-domain)
    float p = dp.x + dp.y;
    p += __shfl_xor(p, 1);
    p += __shfl_xor(p, 2);
    p += __shfl_xor(p, 4);            // 8-lane head group holds the logit
#if __has_builtin(__builtin_amdgcn_exp2f)
    float e = valid ? __builtin_amdgcn_exp2f(p) : 0.f;
#else
    float e = valid ? __expf(p * 0.6931471805599453f) : 0.f;
#endif
    l += e;
    o01 = o01 + e * a;                // pk_fma
    o23 = o23 + e * b;
  };
  auto fetch = [&](int j, uint2& qq, float& ww) {
    int jc = min(j, deg32 - 1);            // clamp: re-fetch = cache hit, no wrap
    unsigned int evj = __shfl(ev, jc, 32);
    ww = (float)(evj & 0xffffu);           // raw ticks
    int s = (int)(evj >> 16);
    if (F8) qq.x = xf[s * 32 + lane];
    else qq = xl2[s * 32 + lane];
  };

  if (deg32 > 0) {
    uint2 q0, q1, q2, q3;
    float w0, w1, w2, w3;
    fetch(0, q0, w0);
    fetch(1, q1, w1);
    fetch(2, q2, w2);
    fetch(3, q3, w3);
    for (int b = 0; b < deg32; b += 4) {
      uint2 c0 = q0, c1 = q1, c2 = q2, c3 = q3;
      float x0 = w0, x1 = w1, x2 = w2, x3 = w3;
      fetch(b + 4, q0, w0);
      fetch(b + 5, q1, w1);
      fetch(b + 6, q2, w2);
      fetch(b + 7, q3, w3);
      edge_body(x0, c0, true);
      edge_body(x1, c1, b + 1 < deg32);
      edge_body(x2, c2, b + 2 < deg32);
      edge_body(x3, c3, b + 3 < deg32);
    }
  }
  if (deg > 32) {  // rare tail (P ~ 1e-4 per node): direct loads
    for (int j = base + 32; j < base + deg; ++j) {
      unsigned int evj = slots[j];
      float w = (float)(evj & 0xffffu);  // raw ticks
      wsum += w;
      int s = (int)(evj >> 16);
      uint2 gc;
      if (F8) gc.x = xf[s * 32 + lane];
      else gc = xl2[s * 32 + lane];
      edge_body(w, gc, true);
    }
  }
  {  // self-loop: attr = mean of incoming edge weights (0 if none); raw-tick mean
    float wself = (deg > 0) ? wsum / (float)deg : 0.f;
    uint2 gs;
    if (F8) gs.x = xf[n * 32 + lane];
    else gs = xl2[n * 32 + lane];
    edge_body(wself, gs, true);
  }

  float inv = 1.f / l;
  float4 o = make_float4(o01.x, o01.y, o23.x, o23.y);
  float4 b4 = ((const float4*)bias)[lane];
  float4 r;
  r.x = fmaf(o.x, inv, b4.x);
  r.y = fmaf(o.y, inv, b4.y);
  r.z = fmaf(o.z, inv, b4.z);
  r.w = fmaf(o.w, inv, b4.w);
  if (FINAL) {
    float4 e4 = ((const float4*)emb)[fi];
    uint2 hh = ((const uint2*)h1p)[fi];
    float4 h4;
    h4.x = blo(hh.x); h4.y = bhi(hh.x); h4.z = blo(hh.y); h4.w = bhi(hh.y);
    float4 cs = ((const float4*)chsum)[lane];
    float4 cq = ((const float4*)chsq)[lane];
    float4 gm = ((const float4*)gamma)[lane];
    float4 bt = ((const float4*)beta)[lane];
    const float invN = 1.f / N_NODES;
    float4 sc4, sh4;
    {
      float mu = cs.x * invN, var = cq.x * invN - mu * mu;
      sc4.x = gm.x * rsqrtf(var + 1e-5f); sh4.x = bt.x - mu * sc4.x;
      mu = cs.y * invN; var = cq.y * invN - mu * mu;
      sc4.y = gm.y * rsqrtf(var + 1e-5f); sh4.y = bt.y - mu * sc4.y;
      mu = cs.z * invN; var = cq.z * invN - mu * mu;
      sc4.z = gm.z * rsqrtf(var + 1e-5f); sh4.z = bt.z - mu * sc4.z;
      mu = cs.w * invN; var = cq.w * invN - mu * mu;
      sc4.w = gm.w * rsqrtf(var + 1e-5f); sh4.w = bt.w - mu * sc4.w;
    }
    float4 h;  // recompute BN+ELU of bf16 h1 (consistent with gemm2's input)
    h.x = fmaf(h4.x, sc4.x, sh4.x);
    h.y = fmaf(h4.y, sc4.y, sh4.y);
    h.z = fmaf(h4.z, sc4.z, sh4.z);
    h.w = fmaf(h4.w, sc4.w, sh4.w);
    h.x = (h.x > 0.f) ? h.x : (__expf(h.x) - 1.f);
    h.y = (h.y > 0.f) ? h.y : (__expf(h.y) - 1.f);
    h.z = (h.z > 0.f) ? h.z : (__expf(h.z) - 1.f);
    h.w = (h.w > 0.f) ? h.w : (__expf(h.w) - 1.f);
    const float k3 = 1.f / 3.f;
    r.x = (e4.x + h.x + r.x) * k3;
    r.y = (e4.y + h.y + r.y) * k3;
    r.z = (e4.z + h.z + r.z) * k3;
    r.w = (e4.w + h.w + r.w) * k3;
    ((float4*)out)[fi] = r;
  } else {
    ((uint2*)out)[fi] = make_uint2(pk2(r.x, r.y), pk2(r.z, r.w));  // h1 bf16
  }
}

// ---------- K4: BN stats over bf16 h1 (uint pair loads + per-channel atomics) --
#define BN_ROWS 200
__global__ __launch_bounds__(256) void k_bnstats(const unsigned short* __restrict__ h1b,
                                                 float* __restrict__ chsum,
                                                 float* __restrict__ chsq) {
  int c2 = threadIdx.x & 63;  // channel pair (2*c2, 2*c2+1)
  int g = threadIdx.x >> 6;   // 0..3
  int r0 = blockIdx.x * BN_ROWS;
  float s0 = 0.f, s1 = 0.f, q0 = 0.f, q1 = 0.f;
  const unsigned int* h32 = (const unsigned int*)h1b;
  for (int r = r0 + g; r < r0 + BN_ROWS; r += 4) {
    unsigned int u = h32[(size_t)r * 64 + c2];
    float a = blo(u), b = bhi(u);
    s0 += a; q0 += a * a;
    s1 += b; q1 += b * b;
  }
  __shared__ float sh[256][4];
  sh[threadIdx.x][0] = s0; sh[threadIdx.x][1] = q0;
  sh[threadIdx.x][2] = s1; sh[threadIdx.x][3] = q1;
  __syncthreads();
  if (g == 0) {
    float ts0 = 0.f, tq0 = 0.f, ts1 = 0.f, tq1 = 0.f;
#pragma unroll
    for (int gg = 0; gg < 4; ++gg) {
      ts0 += sh[gg * 64 + c2][0]; tq0 += sh[gg * 64 + c2][1];
      ts1 += sh[gg * 64 + c2][2]; tq1 += sh[gg * 64 + c2][3];
    }
    atomicAdd(chsum + 2 * c2, ts0);
    atomicAdd(chsq + 2 * c2, tq0);
    atomicAdd(chsum + 2 * c2 + 1, ts1);
    atomicAdd(chsq + 2 * c2 + 1, tq1);
  }
}

extern "C" void kernel_launch(void* const* d_in, const int* in_sizes, int n_in,
                              void* d_out, int out_size, void* d_ws, size_t ws_size,
                              hipStream_t stream) {
  const float* emb = (const float*)d_in[0];
  const int* ei = (const int*)d_in[1];
  const float* ew = (const float*)d_in[2];
  const float* Wl1 = (const float*)d_in[3];
  const float* bl1 = (const float*)d_in[4];
  const float* Wr1 = (const float*)d_in[5];
  const float* br1 = (const float*)d_in[6];
  const float* We1 = (const float*)d_in[7];
  const float* att1 = (const float*)d_in[8];
  const float* bias1 = (const float*)d_in[9];
  const float* gamma1 = (const float*)d_in[10];
  const float* beta1 = (const float*)d_in[11];
  const float* Wl2 = (const float*)d_in[12];
  const float* bl2 = (const float*)d_in[13];
  const float* Wr2 = (const float*)d_in[14];
  const float* br2 = (const float*)d_in[15];
  const float* We2 = (const float*)d_in[16];
  const float* att2 = (const float*)d_in[17];
  const float* bias2 = (const float*)d_in[18];
  float* out = (float*)d_out;

  char* wsb = (char*)d_ws;
  size_t off = 0;
  auto alloc = [&](size_t bytes) -> void* {
    void* p = (void*)(wsb + off);
    off += (bytes + 255) & ~(size_t)255;
    return p;
  };
  int* cursor = (int*)alloc((size_t)N_NODES * 4);                           // 200 KB dense
  float* chsum = (float*)alloc(HC * 4);
  float* chsq = (float*)alloc(HC * 4);
  unsigned short* WtAll = (unsigned short*)alloc((size_t)4 * HC * HC * 2);  // 128 KB
  unsigned int* counts32 = (unsigned int*)alloc((size_t)NCHK * NW * 4);     // 6.4 MB
  unsigned int* bases32 = (unsigned int*)alloc((size_t)NCHK * NW * 4);      // 6.4 MB
  unsigned int* slots = (unsigned int*)alloc((size_t)N_NODES * SLOT * 4);   // 12.8 MB
  unsigned short* xlb = (unsigned short*)alloc((size_t)N_NODES * HC * 2);   // bf16 xl1
  unsigned char* xlf8 = (unsigned char*)alloc((size_t)N_NODES * HC);        // fp8 xl2
  float* xr = (float*)alloc((size_t)N_NODES * HC * 4);
  unsigned short* h1b = (unsigned short*)alloc((size_t)N_NODES * HC * 2);   // bf16 h1
  int* counts2 = (int*)alloc((size_t)NB2 * 72 * 4);                         // 28 KB
  int* bases2 = (int*)alloc((size_t)NB2 * 72 * 4);                          // 28 KB
  int* perm = (int*)alloc((size_t)N_NODES * 4);                             // 200 KB

  // wprep + 2D histogram fused (256 blocks)
  k_histprep<<<NSCAT, 256, 0, stream>>>(Wl1, Wr1, Wl2, Wr2, WtAll, chsum, chsq,
                                        ei, counts32);
  // edge prefix + per-block degree histogram
  k_scan<<<NB2, 256, 0, stream>>>(counts32, bases32, cursor, counts2);
  k_dprefix<<<1, 256, 0, stream>>>(counts2, bases2);
  // edge slot scatter + layer-1 GEMM + degree-sort scatter (one kernel)
  k_scat_g1<<<NSCAT + NBX + NB2, 256, 0, stream>>>(ei, ew, bases32, slots, emb,
                                                   WtAll, bl1, br1, xlb, xr,
                                                   cursor, bases2, perm);
  k_gat<0, 0><<<N_NODES / 8, 256, 0, stream>>>(xlb, xr, cursor, slots, perm, We1,
                                               att1, bias1, (void*)h1b, nullptr,
                                               nullptr, nullptr, nullptr, nullptr,
                                               nullptr);
  k_bnstats<<<N_NODES / BN_ROWS, 256, 0, stream>>>(h1b, chsum, chsq);
  k_gemm2<<<NBX, 256, 0, stream>>>(h1b, WtAll + 2 * HC * HC, bl2, br2, xlf8, xr,
                                   chsum, chsq, gamma1, beta1);
  k_gat<1, 1><<<N_NODES / 8, 256, 0, stream>>>(xlf8, xr, cursor, slots, perm, We2,
                                               att2, bias2, (void*)out, emb, h1b,
                                               chsum, chsq, gamma1, beta1);
}